// Round 1
// baseline (1277.059 us; speedup 1.0000x reference)
//
#include <hip/hip_runtime.h>
#include <hip/hip_bf16.h>
#include <stdint.h>

typedef unsigned int uint;
typedef unsigned short ushort;

#define NB 4
#define SL 4096
#define EMB 1024
#define NH 16
#define DH 64
#define WIN 256
#define OVL 32
#define NW 16
#define NTOK (NB * SL)

// bf16 helpers: pair packed in a uint (little-endian: elem0 = low 16 bits)
__device__ __forceinline__ float bf_lo(uint u) { return __uint_as_float(u << 16); }
__device__ __forceinline__ float bf_hi(uint u) { return __uint_as_float(u & 0xffff0000u); }
__device__ __forceinline__ ushort f2bf(float x) {  // round-to-nearest-even
  uint u = __float_as_uint(x);
  u += 0x7fffu + ((u >> 16) & 1u);
  return (ushort)(u >> 16);
}

// ---------------------------------------------------------------------------
// Kernel 1: per-head QKV projection.
// q[n,l,h,e] = sum_d x[n,l,h*64+d] * W[e,d]; W shared across heads.
// Thread role: (h = t>>4, eq = t&15) computes e = eq + 16*i (i=0..3) for 4
// tokens at once -> 64 FMA per 8 ds_read_b128 (VALU-bound).
// Output layout (bf16): [n][H][L][d] so attention reads contiguous rows.
// ---------------------------------------------------------------------------
__global__ __launch_bounds__(256) void qkv_proj(
    const float* __restrict__ qin, const float* __restrict__ kin,
    const float* __restrict__ vin,
    const float* __restrict__ Wq, const float* __restrict__ Wk,
    const float* __restrict__ Wv,
    ushort* __restrict__ qo, ushort* __restrict__ ko, ushort* __restrict__ vo) {
  // sW layout: [(d4*64 + e)*4 + c] = W[e][d4*4+c]  (16 lanes read 16
  // consecutive float4s -> 256B contiguous, conflict-free)
  __shared__ float sW[4096];
  // sx layout: [tk][h*68 + d]  (pad 68 so the 4 h-broadcast addrs per
  // instruction land in distinct bank groups)
  __shared__ float sx[4][16 * 68];
  const int t = threadIdx.x;
  const int h = t >> 4, eq = t & 15;

  const float* ins[3] = {qin, kin, vin};
  const float* Ws[3] = {Wq, Wk, Wv};
  ushort* outs[3] = {qo, ko, vo};

  for (int p = 0; p < 3; ++p) {
    __syncthreads();  // protect sW reuse across p
    const float* W = Ws[p];
    for (int i = t; i < 4096; i += 256) {
      int c = i & 3, e = (i >> 2) & 63, d4 = i >> 8;
      sW[i] = W[e * 64 + d4 * 4 + c];
    }
    const float* src = ins[p];
    ushort* dst = outs[p];
    for (int quad = blockIdx.x; quad < NTOK / 4; quad += gridDim.x) {
      const int tok0 = quad * 4;
      __syncthreads();  // protect sx reuse (and first-iter sW)
      for (int s = t; s < 1024; s += 256) {
        int tk = s >> 8, i4 = s & 255;
        float4 x4 = ((const float4*)(src + (size_t)(tok0 + tk) * 1024))[i4];
        int hh = i4 >> 4, d0 = (i4 & 15) * 4;
        *(float4*)&sx[tk][hh * 68 + d0] = x4;
      }
      __syncthreads();
      float acc[4][4];
#pragma unroll
      for (int a = 0; a < 4; ++a)
#pragma unroll
        for (int b = 0; b < 4; ++b) acc[a][b] = 0.f;
#pragma unroll
      for (int d4 = 0; d4 < 16; ++d4) {
        float4 w4[4];
#pragma unroll
        for (int i = 0; i < 4; ++i)
          w4[i] = *(const float4*)&sW[(d4 * 64 + eq + 16 * i) * 4];
#pragma unroll
        for (int tk = 0; tk < 4; ++tk) {
          float4 x4 = *(const float4*)&sx[tk][h * 68 + d4 * 4];
#pragma unroll
          for (int i = 0; i < 4; ++i)
            acc[tk][i] += x4.x * w4[i].x + x4.y * w4[i].y + x4.z * w4[i].z +
                          x4.w * w4[i].w;
        }
      }
#pragma unroll
      for (int tk = 0; tk < 4; ++tk) {
        int tok = tok0 + tk;
        int nb = tok >> 12, l = tok & 4095;
        size_t base = ((size_t)(nb * NH + h) * SL + l) * DH;
#pragma unroll
        for (int i = 0; i < 4; ++i)
          dst[base + eq + 16 * i] = f2bf(acc[tk][i]);
      }
    }
  }
}

// ---------------------------------------------------------------------------
// Kernel 2: overlapping-window attention. One block per (n, w, h); thread =
// query. K/V chunks (64 rows x 64 d, fp32 after unpack) staged in LDS; all
// inner LDS reads are wave-uniform broadcasts (conflict-free). Online softmax
// with rare-rescale branch; boundary keys (idx outside [OVL, OVL+L)) skipped
// entirely (== -inf logits); masked queries get -1e10 pre-scale logits.
// ---------------------------------------------------------------------------
__global__ __launch_bounds__(256) void attn_win(
    const ushort* __restrict__ qws, const ushort* __restrict__ kws,
    const ushort* __restrict__ vws, const int* __restrict__ mask,
    ushort* __restrict__ att) {
  __shared__ float sk[64][64];
  __shared__ float sv[64][64];
  const int t = threadIdx.x;
  const int bid = blockIdx.x;
  const int h = bid & 15, w = (bid >> 4) & 15, nb = bid >> 8;
  const size_t headbase = (size_t)(nb * NH + h) * SL;
  const int l = w * WIN + t;

  float qreg[64];
  {
    const uint4* qrow = (const uint4*)(qws + (headbase + l) * DH);
#pragma unroll
    for (int r = 0; r < 8; ++r) {
      uint4 u = qrow[r];
      qreg[r * 8 + 0] = bf_lo(u.x); qreg[r * 8 + 1] = bf_hi(u.x);
      qreg[r * 8 + 2] = bf_lo(u.y); qreg[r * 8 + 3] = bf_hi(u.y);
      qreg[r * 8 + 4] = bf_lo(u.z); qreg[r * 8 + 5] = bf_hi(u.z);
      qreg[r * 8 + 6] = bf_lo(u.w); qreg[r * 8 + 7] = bf_hi(u.w);
    }
  }
  const int mflag = mask[nb * SL + l];
  float m = -INFINITY, lsum = 0.f;
  float acc[64];
#pragma unroll
  for (int d = 0; d < 64; ++d) acc[d] = 0.f;

  const int gk0 = w * WIN - OVL;
  for (int c = 0; c < 5; ++c) {
    __syncthreads();
    for (int s = t; s < 512; s += 256) {
      int r = s >> 3, j = s & 7;
      int gk = gk0 + c * 64 + r;
      uint4 ku = make_uint4(0u, 0u, 0u, 0u);
      uint4 vu = make_uint4(0u, 0u, 0u, 0u);
      if (gk >= 0 && gk < SL) {
        ku = ((const uint4*)(kws + (headbase + gk) * DH))[j];
        vu = ((const uint4*)(vws + (headbase + gk) * DH))[j];
      }
      float* kd = &sk[r][j * 8];
      kd[0] = bf_lo(ku.x); kd[1] = bf_hi(ku.x);
      kd[2] = bf_lo(ku.y); kd[3] = bf_hi(ku.y);
      kd[4] = bf_lo(ku.z); kd[5] = bf_hi(ku.z);
      kd[6] = bf_lo(ku.w); kd[7] = bf_hi(ku.w);
      float* vd = &sv[r][j * 8];
      vd[0] = bf_lo(vu.x); vd[1] = bf_hi(vu.x);
      vd[2] = bf_lo(vu.y); vd[3] = bf_hi(vu.y);
      vd[4] = bf_lo(vu.z); vd[5] = bf_hi(vu.z);
      vd[6] = bf_lo(vu.w); vd[7] = bf_hi(vu.w);
    }
    __syncthreads();
    const int cbase = gk0 + c * 64;
    const int jlo = max(0, -cbase);
    const int jhi = min(64, SL - cbase);
    for (int j = jlo; j < jhi; ++j) {
      float s0 = 0.f, s1 = 0.f, s2 = 0.f, s3 = 0.f;
#pragma unroll
      for (int d4 = 0; d4 < 16; ++d4) {
        float4 k4 = *(const float4*)&sk[j][d4 * 4];
        s0 += qreg[d4 * 4 + 0] * k4.x;
        s1 += qreg[d4 * 4 + 1] * k4.y;
        s2 += qreg[d4 * 4 + 2] * k4.z;
        s3 += qreg[d4 * 4 + 3] * k4.w;
      }
      float s = ((s0 + s1) + (s2 + s3)) * 0.125f;
      if (!mflag) s = -1.25e9f;  // -1e10 applied before the /8 scale
      if (s > m) {
        float corr = __expf(m - s);  // first key: exp(-inf)=0, zeroes state
        lsum *= corr;
#pragma unroll
        for (int d = 0; d < 64; ++d) acc[d] *= corr;
        m = s;
      }
      float p = __expf(s - m);
      lsum += p;
#pragma unroll
      for (int d4 = 0; d4 < 16; ++d4) {
        float4 v4 = *(const float4*)&sv[j][d4 * 4];
        acc[d4 * 4 + 0] += p * v4.x;
        acc[d4 * 4 + 1] += p * v4.y;
        acc[d4 * 4 + 2] += p * v4.z;
        acc[d4 * 4 + 3] += p * v4.w;
      }
    }
  }
  const float inv = 1.f / lsum;
  // att layout: [n][L][E] (token-major) so the final GEMM has row-major A
  uint4* orow = (uint4*)(att + ((size_t)(nb * SL + l)) * EMB + h * DH);
#pragma unroll
  for (int r = 0; r < 8; ++r) {
    uint4 o;
    o.x = (uint)f2bf(acc[r * 8 + 0] * inv) | ((uint)f2bf(acc[r * 8 + 1] * inv) << 16);
    o.y = (uint)f2bf(acc[r * 8 + 2] * inv) | ((uint)f2bf(acc[r * 8 + 3] * inv) << 16);
    o.z = (uint)f2bf(acc[r * 8 + 4] * inv) | ((uint)f2bf(acc[r * 8 + 5] * inv) << 16);
    o.w = (uint)f2bf(acc[r * 8 + 6] * inv) | ((uint)f2bf(acc[r * 8 + 7] * inv) << 16);
    orow[r] = o;
  }
}

// ---------------------------------------------------------------------------
// Kernel 3: C[16384][1024] = A(bf16) @ Wf^T + bf  (both A and Wf are K-major).
// 64x64 tile, 4x4 microtile/thread, K-chunk 32, LDS stride 68 (pad) for
// conflict-free float4 reads. fp32 vector FMA (round 2: bf16 MFMA).
// ---------------------------------------------------------------------------
__global__ __launch_bounds__(256) void final_gemm(
    const ushort* __restrict__ A, const float* __restrict__ Wf,
    const float* __restrict__ bias, float* __restrict__ C) {
  __shared__ float sA[32 * 68];  // [k][m]
  __shared__ float sB[32 * 68];  // [k][n]
  const int t = threadIdx.x;
  const int tx = t & 15, ty = t >> 4;
  const int n0 = blockIdx.x * 64, m0 = blockIdx.y * 64;
  float acc[4][4];
#pragma unroll
  for (int i = 0; i < 4; ++i)
#pragma unroll
    for (int j = 0; j < 4; ++j) acc[i][j] = 0.f;

  for (int k0 = 0; k0 < EMB; k0 += 32) {
    __syncthreads();
    for (int s = t; s < 512; s += 256) {
      int r = s >> 3, j = s & 7;
      uint2 au = *(const uint2*)(A + (size_t)(m0 + r) * EMB + k0 + j * 4);
      sA[(j * 4 + 0) * 68 + r] = bf_lo(au.x);
      sA[(j * 4 + 1) * 68 + r] = bf_hi(au.x);
      sA[(j * 4 + 2) * 68 + r] = bf_lo(au.y);
      sA[(j * 4 + 3) * 68 + r] = bf_hi(au.y);
      float4 b4 = *(const float4*)(Wf + (size_t)(n0 + r) * EMB + k0 + j * 4);
      sB[(j * 4 + 0) * 68 + r] = b4.x;
      sB[(j * 4 + 1) * 68 + r] = b4.y;
      sB[(j * 4 + 2) * 68 + r] = b4.z;
      sB[(j * 4 + 3) * 68 + r] = b4.w;
    }
    __syncthreads();
#pragma unroll
    for (int kk = 0; kk < 32; ++kk) {
      float4 a4 = *(const float4*)&sA[kk * 68 + ty * 4];
      float4 b4 = *(const float4*)&sB[kk * 68 + tx * 4];
      float av[4] = {a4.x, a4.y, a4.z, a4.w};
      float bv[4] = {b4.x, b4.y, b4.z, b4.w};
#pragma unroll
      for (int i = 0; i < 4; ++i)
#pragma unroll
        for (int j = 0; j < 4; ++j) acc[i][j] += av[i] * bv[j];
    }
  }
  float4 bb = *(const float4*)&bias[n0 + tx * 4];
#pragma unroll
  for (int i = 0; i < 4; ++i) {
    float4 o;
    o.x = acc[i][0] + bb.x;
    o.y = acc[i][1] + bb.y;
    o.z = acc[i][2] + bb.z;
    o.w = acc[i][3] + bb.w;
    *(float4*)&C[(size_t)(m0 + ty * 4 + i) * EMB + n0 + tx * 4] = o;
  }
}

extern "C" void kernel_launch(void* const* d_in, const int* in_sizes, int n_in,
                              void* d_out, int out_size, void* d_ws,
                              size_t ws_size, hipStream_t stream) {
  const float* values  = (const float*)d_in[0];
  const float* keys    = (const float*)d_in[1];
  const float* queries = (const float*)d_in[2];
  const int*   mask    = (const int*)d_in[3];
  const float* Wv = (const float*)d_in[4];
  const float* Wk = (const float*)d_in[5];
  const float* Wq = (const float*)d_in[6];
  const float* Wf = (const float*)d_in[7];
  const float* bfv = (const float*)d_in[8];
  float* out = (float*)d_out;

  // Workspace (bf16): q,k,v = [n][H][L][d] (16.7M elems each), att = [n][L][E]
  // Total 4 * 16,777,216 * 2B = 128 MB.
  ushort* ws = (ushort*)d_ws;
  ushort* q_ws = ws;
  ushort* k_ws = ws + (size_t)16777216;
  ushort* v_ws = ws + (size_t)33554432;
  ushort* a_ws = ws + (size_t)50331648;

  qkv_proj<<<512, 256, 0, stream>>>(queries, keys, values, Wq, Wk, Wv, q_ws,
                                    k_ws, v_ws);
  attn_win<<<NB * NW * NH, 256, 0, stream>>>(q_ws, k_ws, v_ws, mask, a_ws);
  final_gemm<<<dim3(EMB / 64, NTOK / 64), 256, 0, stream>>>(a_ws, Wf, bfv, out);
}

// Round 2
// 522.347 us; speedup vs baseline: 2.4448x; 2.4448x over previous
//
#include <hip/hip_runtime.h>
#include <hip/hip_bf16.h>
#include <stdint.h>

typedef unsigned int uint;
typedef unsigned short ushort;

#define NB 4
#define SL 4096
#define EMB 1024
#define NH 16
#define DH 64
#define WIN 256
#define OVL 32
#define NW 16
#define NTOK (NB * SL)

typedef __attribute__((ext_vector_type(8))) short short8;   // 8 bf16 = 4 VGPR
typedef __attribute__((ext_vector_type(4))) float float4v;  // 4 fp32 acc

#define AS1 __attribute__((address_space(1)))
#define AS3 __attribute__((address_space(3)))

// bf16 helpers
__device__ __forceinline__ float bf_lo(uint u) { return __uint_as_float(u << 16); }
__device__ __forceinline__ float bf_hi(uint u) { return __uint_as_float(u & 0xffff0000u); }
__device__ __forceinline__ float bf2f(ushort s) { return __uint_as_float((uint)s << 16); }
__device__ __forceinline__ ushort f2bf(float x) {  // round-to-nearest-even
  uint u = __float_as_uint(x);
  u += 0x7fffu + ((u >> 16) & 1u);
  return (ushort)(u >> 16);
}

// ---------------------------------------------------------------------------
// Kernel 1: per-head QKV projection (unchanged from round 1; round-3 target).
// Output layout (bf16): [n][H][L][d].
// ---------------------------------------------------------------------------
__global__ __launch_bounds__(256) void qkv_proj(
    const float* __restrict__ qin, const float* __restrict__ kin,
    const float* __restrict__ vin,
    const float* __restrict__ Wq, const float* __restrict__ Wk,
    const float* __restrict__ Wv,
    ushort* __restrict__ qo, ushort* __restrict__ ko, ushort* __restrict__ vo) {
  __shared__ float sW[4096];
  __shared__ float sx[4][16 * 68];
  const int t = threadIdx.x;
  const int h = t >> 4, eq = t & 15;

  const float* ins[3] = {qin, kin, vin};
  const float* Ws[3] = {Wq, Wk, Wv};
  ushort* outs[3] = {qo, ko, vo};

  for (int p = 0; p < 3; ++p) {
    __syncthreads();
    const float* W = Ws[p];
    for (int i = t; i < 4096; i += 256) {
      int c = i & 3, e = (i >> 2) & 63, d4 = i >> 8;
      sW[i] = W[e * 64 + d4 * 4 + c];
    }
    const float* src = ins[p];
    ushort* dst = outs[p];
    for (int quad = blockIdx.x; quad < NTOK / 4; quad += gridDim.x) {
      const int tok0 = quad * 4;
      __syncthreads();
      for (int s = t; s < 1024; s += 256) {
        int tk = s >> 8, i4 = s & 255;
        float4 x4 = ((const float4*)(src + (size_t)(tok0 + tk) * 1024))[i4];
        int hh = i4 >> 4, d0 = (i4 & 15) * 4;
        *(float4*)&sx[tk][hh * 68 + d0] = x4;
      }
      __syncthreads();
      float acc[4][4];
#pragma unroll
      for (int a = 0; a < 4; ++a)
#pragma unroll
        for (int b = 0; b < 4; ++b) acc[a][b] = 0.f;
#pragma unroll
      for (int d4 = 0; d4 < 16; ++d4) {
        float4 w4[4];
#pragma unroll
        for (int i = 0; i < 4; ++i)
          w4[i] = *(const float4*)&sW[(d4 * 64 + eq + 16 * i) * 4];
#pragma unroll
        for (int tk = 0; tk < 4; ++tk) {
          float4 x4 = *(const float4*)&sx[tk][h * 68 + d4 * 4];
#pragma unroll
          for (int i = 0; i < 4; ++i)
            acc[tk][i] += x4.x * w4[i].x + x4.y * w4[i].y + x4.z * w4[i].z +
                          x4.w * w4[i].w;
        }
      }
#pragma unroll
      for (int tk = 0; tk < 4; ++tk) {
        int tok = tok0 + tk;
        int nb = tok >> 12, l = tok & 4095;
        size_t base = ((size_t)(nb * NH + h) * SL + l) * DH;
#pragma unroll
        for (int i = 0; i < 4; ++i)
          dst[base + eq + 16 * i] = f2bf(acc[tk][i]);
      }
    }
  }
}

// ---------------------------------------------------------------------------
// Kernel 2: flash-style MFMA windowed attention. Block = (n,w,h), 4 waves,
// wave = 64 queries. Layouts per verified docs:
//   A-frag: A[m=lane&15][k=quad*8+j]   B-frag: B^rowmajor[n=lane&15][k=...]
//   C/D:    row = quad*4+reg, col = lane&15
// P goes C-layout -> LDS -> A-layout (m120-verified round trip).
// All LDS row strides = 72 ushorts (144B = 9 superbanks, conflict-free b128).
// exp2 domain: scale = 0.125*log2(e) applied to S post-MFMA.
// ---------------------------------------------------------------------------
__global__ __launch_bounds__(256) void attn_win_mfma(
    const ushort* __restrict__ qws, const ushort* __restrict__ kws,
    const ushort* __restrict__ vws, const int* __restrict__ mask,
    ushort* __restrict__ att) {
  __shared__ alignas(16) ushort sk[64 * 72];      // K chunk [key][d]
  __shared__ alignas(16) ushort svT[64 * 72];     // V chunk transposed [d][key]
  __shared__ alignas(16) ushort sp[4 * 64 * 72];  // per-wave P [q][key]
  __shared__ float sm[256];                       // per-query mask flag

  const int t = threadIdx.x;
  const int wid = t >> 6, lane = t & 63, quad = lane >> 4, l16 = lane & 15;
  const int bid = blockIdx.x;
  const int h = bid & 15, w = (bid >> 4) & 15, nb = bid >> 8;
  const size_t headbase = (size_t)(nb * NH + h) * SL;
  const int q0 = w * WIN + wid * 64;  // first query row of this wave

  sm[t] = (float)mask[nb * SL + w * WIN + t];

  // Q fragments (A-layout), resident in registers for the whole kernel
  short8 qf[4][2];
#pragma unroll
  for (int mt = 0; mt < 4; ++mt)
#pragma unroll
    for (int kh = 0; kh < 2; ++kh)
      qf[mt][kh] = *(const short8*)(qws + (headbase + q0 + mt * 16 + l16) * DH +
                                    kh * 32 + quad * 8);

  float4v Of[4][4];
#pragma unroll
  for (int mt = 0; mt < 4; ++mt)
#pragma unroll
    for (int dt = 0; dt < 4; ++dt) Of[mt][dt] = (float4v){0.f, 0.f, 0.f, 0.f};
  float mrow[16], lrow[16];
#pragma unroll
  for (int i = 0; i < 16; ++i) { mrow[i] = -INFINITY; lrow[i] = 0.f; }

  ushort* spw = sp + wid * 64 * 72;
  const int gk0 = w * WIN - OVL;
  const float CSC = 0.18033688f;  // 0.125 * log2(e)

  for (int c = 0; c < 5; ++c) {
    __syncthreads();
    const int cbase = gk0 + c * 64;
    // stage K [key][d] and V^T [d][key]
    for (int s = t; s < 512; s += 256) {
      int key = s & 63, dj = s >> 6;
      int gk = cbase + key;
      uint4 kq = make_uint4(0u, 0u, 0u, 0u);
      uint4 vq = make_uint4(0u, 0u, 0u, 0u);
      if ((unsigned)gk < (unsigned)SL) {
        kq = *(const uint4*)(kws + (headbase + gk) * DH + dj * 8);
        vq = *(const uint4*)(vws + (headbase + gk) * DH + dj * 8);
      }
      *(uint4*)&sk[key * 72 + dj * 8] = kq;
      svT[(dj * 8 + 0) * 72 + key] = (ushort)(vq.x & 0xffffu);
      svT[(dj * 8 + 1) * 72 + key] = (ushort)(vq.x >> 16);
      svT[(dj * 8 + 2) * 72 + key] = (ushort)(vq.y & 0xffffu);
      svT[(dj * 8 + 3) * 72 + key] = (ushort)(vq.y >> 16);
      svT[(dj * 8 + 4) * 72 + key] = (ushort)(vq.z & 0xffffu);
      svT[(dj * 8 + 5) * 72 + key] = (ushort)(vq.z >> 16);
      svT[(dj * 8 + 6) * 72 + key] = (ushort)(vq.w & 0xffffu);
      svT[(dj * 8 + 7) * 72 + key] = (ushort)(vq.w >> 16);
    }
    __syncthreads();

    // S = Q K^T
    float4v Sf[4][4];
#pragma unroll
    for (int mt = 0; mt < 4; ++mt)
#pragma unroll
      for (int nt = 0; nt < 4; ++nt) Sf[mt][nt] = (float4v){0.f, 0.f, 0.f, 0.f};
#pragma unroll
    for (int kh = 0; kh < 2; ++kh) {
      short8 kf[4];
#pragma unroll
      for (int nt = 0; nt < 4; ++nt)
        kf[nt] = *(const short8*)&sk[(nt * 16 + l16) * 72 + kh * 32 + quad * 8];
#pragma unroll
      for (int mt = 0; mt < 4; ++mt)
#pragma unroll
        for (int nt = 0; nt < 4; ++nt)
          Sf[mt][nt] = __builtin_amdgcn_mfma_f32_16x16x32_bf16(
              qf[mt][kh], kf[nt], Sf[mt][nt], 0, 0, 0);
    }

    // scale + query mask + key-validity mask (key-invalid wins, as in ref)
#pragma unroll
    for (int nt = 0; nt < 4; ++nt) {
      const int gkey = cbase + nt * 16 + l16;
      const bool kvalid = ((unsigned)gkey < (unsigned)SL);
#pragma unroll
      for (int mt = 0; mt < 4; ++mt)
#pragma unroll
        for (int reg = 0; reg < 4; ++reg) {
          float sv = Sf[mt][nt][reg] * CSC;
          if (sm[wid * 64 + mt * 16 + quad * 4 + reg] == 0.f) sv = -1.803e9f;
          if (!kvalid) sv = -INFINITY;
          Sf[mt][nt][reg] = sv;
        }
    }

    // online softmax per row; write P (bf16) to LDS in [q][key]
#pragma unroll
    for (int mt = 0; mt < 4; ++mt)
#pragma unroll
      for (int reg = 0; reg < 4; ++reg) {
        const int ri = mt * 4 + reg;
        float mx = fmaxf(fmaxf(Sf[mt][0][reg], Sf[mt][1][reg]),
                         fmaxf(Sf[mt][2][reg], Sf[mt][3][reg]));
        mx = fmaxf(mx, __shfl_xor(mx, 1));
        mx = fmaxf(mx, __shfl_xor(mx, 2));
        mx = fmaxf(mx, __shfl_xor(mx, 4));
        mx = fmaxf(mx, __shfl_xor(mx, 8));
        const float mn = fmaxf(mrow[ri], mx);
        const float alpha = exp2f(mrow[ri] - mn);
        mrow[ri] = mn;
        float rs = 0.f;
#pragma unroll
        for (int nt = 0; nt < 4; ++nt) {
          float p = exp2f(Sf[mt][nt][reg] - mn);
          ushort pb = f2bf(p);
          rs += bf2f(pb);  // sum the rounded values for consistency with PV
          spw[(mt * 16 + quad * 4 + reg) * 72 + nt * 16 + l16] = pb;
        }
        rs += __shfl_xor(rs, 1);
        rs += __shfl_xor(rs, 2);
        rs += __shfl_xor(rs, 4);
        rs += __shfl_xor(rs, 8);
        lrow[ri] = lrow[ri] * alpha + rs;
#pragma unroll
        for (int dt = 0; dt < 4; ++dt) Of[mt][dt][reg] *= alpha;
      }

    // O += P V   (P from LDS in A-layout, V^T rows give B-frags)
#pragma unroll
    for (int kh = 0; kh < 2; ++kh) {
      short8 pa[4], pb[4];
#pragma unroll
      for (int mt = 0; mt < 4; ++mt)
        pa[mt] = *(const short8*)&spw[(mt * 16 + l16) * 72 + kh * 32 + quad * 8];
#pragma unroll
      for (int dt = 0; dt < 4; ++dt)
        pb[dt] = *(const short8*)&svT[(dt * 16 + l16) * 72 + kh * 32 + quad * 8];
#pragma unroll
      for (int mt = 0; mt < 4; ++mt)
#pragma unroll
        for (int dt = 0; dt < 4; ++dt)
          Of[mt][dt] = __builtin_amdgcn_mfma_f32_16x16x32_bf16(
              pa[mt], pb[dt], Of[mt][dt], 0, 0, 0);
    }
  }

  // epilogue: normalize, write att [token][E] bf16
#pragma unroll
  for (int mt = 0; mt < 4; ++mt)
#pragma unroll
    for (int reg = 0; reg < 4; ++reg) {
      const float invl = 1.f / lrow[mt * 4 + reg];
      const size_t token = (size_t)nb * SL + q0 + mt * 16 + quad * 4 + reg;
#pragma unroll
      for (int dt = 0; dt < 4; ++dt)
        att[token * EMB + h * DH + dt * 16 + l16] =
            f2bf(Of[mt][dt][reg] * invl);
    }
}

// ---------------------------------------------------------------------------
// Kernel 3a: Wf fp32 -> bf16 (1M elems)
// ---------------------------------------------------------------------------
__global__ __launch_bounds__(256) void wf_cvt(const float* __restrict__ Wf,
                                              ushort* __restrict__ o) {
  const int i = blockIdx.x * 256 + threadIdx.x;  // 262144 float4 groups
  float4 f = ((const float4*)Wf)[i];
  uint2 u;
  u.x = (uint)f2bf(f.x) | ((uint)f2bf(f.y) << 16);
  u.y = (uint)f2bf(f.z) | ((uint)f2bf(f.w) << 16);
  ((uint2*)o)[i] = u;
}

// ---------------------------------------------------------------------------
// Kernel 3b: C[16384][1024] = A(bf16) @ Bt(bf16)^T + bias. m97 structure:
// 128x128 tile, BK=64, global_load_lds width-16 staging (lane-order layout,
// no padding), 2x2 wave grid, 4x4 16x16 C-frags per wave.
// ---------------------------------------------------------------------------
#define GBK 64
__global__ __launch_bounds__(256) void final_gemm_mfma(
    const ushort* __restrict__ A, const ushort* __restrict__ Bt,
    const float* __restrict__ bias, float* __restrict__ C) {
  __shared__ alignas(16) ushort sA[128 * GBK];  // [m][k], row = 128B
  __shared__ alignas(16) ushort sB[128 * GBK];  // [n][k]
  const int t = threadIdx.x;
  const int wid = t >> 6, lane = t & 63, quad = lane >> 4, l16 = lane & 15;
  const int n0 = blockIdx.x * 128, m0 = blockIdx.y * 128;
  const int wm = (wid & 1) * 64, wn = (wid >> 1) * 64;

  float4v acc[4][4];
#pragma unroll
  for (int i = 0; i < 4; ++i)
#pragma unroll
    for (int j = 0; j < 4; ++j) acc[i][j] = (float4v){0.f, 0.f, 0.f, 0.f};

  const int arow = lane >> 3;       // 0..7 rows per 1KB segment
  const int acol = (lane & 7) * 8;  // k-elem offset

  for (int k0 = 0; k0 < EMB; k0 += GBK) {
    __syncthreads();
#pragma unroll
    for (int seg = 0; seg < 4; ++seg) {
      const int r = wid * 32 + seg * 8;  // wave-uniform base row
      __builtin_amdgcn_global_load_lds(
          (AS1 const void*)(A + (size_t)(m0 + r + arow) * EMB + k0 + acol),
          (AS3 void*)&sA[r * GBK], 16, 0, 0);
      __builtin_amdgcn_global_load_lds(
          (AS1 const void*)(Bt + (size_t)(n0 + r + arow) * EMB + k0 + acol),
          (AS3 void*)&sB[r * GBK], 16, 0, 0);
    }
    __syncthreads();
#pragma unroll
    for (int kk = 0; kk < GBK; kk += 32) {
      short8 af[4], bfr[4];
#pragma unroll
      for (int i = 0; i < 4; ++i)
        af[i] = *(const short8*)&sA[(wm + i * 16 + l16) * GBK + kk + quad * 8];
#pragma unroll
      for (int j = 0; j < 4; ++j)
        bfr[j] = *(const short8*)&sB[(wn + j * 16 + l16) * GBK + kk + quad * 8];
#pragma unroll
      for (int i = 0; i < 4; ++i)
#pragma unroll
        for (int j = 0; j < 4; ++j)
          acc[i][j] = __builtin_amdgcn_mfma_f32_16x16x32_bf16(af[i], bfr[j],
                                                              acc[i][j], 0, 0, 0);
    }
  }

  float bv[4];
#pragma unroll
  for (int j = 0; j < 4; ++j) bv[j] = bias[n0 + wn + j * 16 + l16];
#pragma unroll
  for (int i = 0; i < 4; ++i)
#pragma unroll
    for (int j = 0; j < 4; ++j)
#pragma unroll
      for (int r = 0; r < 4; ++r)
        C[(size_t)(m0 + wm + i * 16 + quad * 4 + r) * EMB + n0 + wn + j * 16 +
          l16] = acc[i][j][r] + bv[j];
}

extern "C" void kernel_launch(void* const* d_in, const int* in_sizes, int n_in,
                              void* d_out, int out_size, void* d_ws,
                              size_t ws_size, hipStream_t stream) {
  const float* values  = (const float*)d_in[0];
  const float* keys    = (const float*)d_in[1];
  const float* queries = (const float*)d_in[2];
  const int*   mask    = (const int*)d_in[3];
  const float* Wv = (const float*)d_in[4];
  const float* Wk = (const float*)d_in[5];
  const float* Wq = (const float*)d_in[6];
  const float* Wf = (const float*)d_in[7];
  const float* bfv = (const float*)d_in[8];
  float* out = (float*)d_out;

  // Workspace (bf16): q,k,v = [n][H][L][d], att = [n][L][E]; 128 MB total.
  // Wf-bf16 reuses the q region (q is dead after attn; stream-ordered).
  ushort* ws = (ushort*)d_ws;
  ushort* q_ws = ws;
  ushort* k_ws = ws + (size_t)16777216;
  ushort* v_ws = ws + (size_t)33554432;
  ushort* a_ws = ws + (size_t)50331648;
  ushort* wf_bf = q_ws;

  qkv_proj<<<512, 256, 0, stream>>>(queries, keys, values, Wq, Wk, Wv, q_ws,
                                    k_ws, v_ws);
  attn_win_mfma<<<NB * NW * NH, 256, 0, stream>>>(q_ws, k_ws, v_ws, mask, a_ws);
  wf_cvt<<<1024, 256, 0, stream>>>(Wf, wf_bf);
  final_gemm_mfma<<<dim3(EMB / 128, NTOK / 128), 256, 0, stream>>>(a_ws, wf_bf,
                                                                   bfv, out);
}

// Round 3
// 455.091 us; speedup vs baseline: 2.8062x; 1.1478x over previous
//
#include <hip/hip_runtime.h>
#include <hip/hip_bf16.h>
#include <stdint.h>

typedef unsigned int uint;
typedef unsigned short ushort;

#define NB 4
#define SL 4096
#define EMB 1024
#define NH 16
#define DH 64
#define WIN 256
#define OVL 32
#define NW 16
#define NTOK (NB * SL)

typedef __attribute__((ext_vector_type(8))) short short8;   // 8 bf16 = 4 VGPR
typedef __attribute__((ext_vector_type(4))) float float4v;  // 4 fp32 acc

#define AS1 __attribute__((address_space(1)))
#define AS3 __attribute__((address_space(3)))

// bf16 helpers
__device__ __forceinline__ float bf2f(ushort s) { return __uint_as_float((uint)s << 16); }
__device__ __forceinline__ ushort f2bf(float x) {  // round-to-nearest-even
  uint u = __float_as_uint(x);
  u += 0x7fffu + ((u >> 16) & 1u);
  return (ushort)(u >> 16);
}
__device__ __forceinline__ uint packbf(float a, float b) {
  return (uint)f2bf(a) | ((uint)f2bf(b) << 16);
}

// ---------------------------------------------------------------------------
// Kernel 1: MFMA QKV projection. Grid (64 token-tiles, 16 heads, 3 proj).
// out[tok][e] = sum_d x[tok][h*64+d] * W[e][d].
// MFMA with A=W (m=e,k=d), B=x (n=tok,k=d) -> D[e][tok]; C-layout gives each
// lane col=tok (l16) and rows e=quad*4+reg, so 4 consecutive e pack into one
// b64 LDS write for the store transpose. Output layout: [n][H][L][d] bf16.
// ---------------------------------------------------------------------------
__global__ __launch_bounds__(256) void qkv_proj_mfma(
    const float* __restrict__ qin, const float* __restrict__ kin,
    const float* __restrict__ vin,
    const float* __restrict__ Wq, const float* __restrict__ Wk,
    const float* __restrict__ Wv,
    ushort* __restrict__ qo, ushort* __restrict__ ko, ushort* __restrict__ vo) {
  __shared__ alignas(16) ushort sx[256 * 72];  // x tile [tok][d], then out [tok][e]
  __shared__ alignas(16) ushort sw[64 * 72];   // W [e][d]
  const int t = threadIdx.x;
  const int wid = t >> 6, lane = t & 63, quad = lane >> 4, l16 = lane & 15;
  const int p = blockIdx.z, h = blockIdx.y;
  const int tok0 = blockIdx.x * 256;

  const float* src = (p == 0) ? qin : ((p == 1) ? kin : vin);
  const float* W   = (p == 0) ? Wq  : ((p == 1) ? Wk  : Wv);
  ushort* dst      = (p == 0) ? qo  : ((p == 1) ? ko  : vo);

  // stage W: 64x64 fp32 -> bf16, rows stride 72
  for (int i = t; i < 1024; i += 256) {
    int e = i >> 4, c4 = i & 15;
    float4 f = *(const float4*)(W + e * 64 + c4 * 4);
    uint2 u;
    u.x = packbf(f.x, f.y);
    u.y = packbf(f.z, f.w);
    *(uint2*)&sw[e * 72 + c4 * 4] = u;
  }
  // stage x tile: 256 tok x 64 d fp32 -> bf16  (rows are 256B contiguous)
  for (int i = t; i < 4096; i += 256) {
    int tok = i >> 4, c4 = i & 15;
    float4 f = *(const float4*)(src + (size_t)(tok0 + tok) * EMB + h * DH + c4 * 4);
    uint2 u;
    u.x = packbf(f.x, f.y);
    u.y = packbf(f.z, f.w);
    *(uint2*)&sx[tok * 72 + c4 * 4] = u;
  }
  __syncthreads();

  // fragments: wave handles its 64-token slab, all 64 e
  short8 wa[4][2], xb[4][2];
#pragma unroll
  for (int mt = 0; mt < 4; ++mt)
#pragma unroll
    for (int kh = 0; kh < 2; ++kh)
      wa[mt][kh] = *(const short8*)&sw[(mt * 16 + l16) * 72 + kh * 32 + quad * 8];
#pragma unroll
  for (int nt = 0; nt < 4; ++nt)
#pragma unroll
    for (int kh = 0; kh < 2; ++kh)
      xb[nt][kh] = *(const short8*)&sx[(wid * 64 + nt * 16 + l16) * 72 + kh * 32 + quad * 8];

  float4v acc[4][4];
#pragma unroll
  for (int i = 0; i < 4; ++i)
#pragma unroll
    for (int j = 0; j < 4; ++j) acc[i][j] = (float4v){0.f, 0.f, 0.f, 0.f};
#pragma unroll
  for (int kh = 0; kh < 2; ++kh)
#pragma unroll
    for (int mt = 0; mt < 4; ++mt)
#pragma unroll
      for (int nt = 0; nt < 4; ++nt)
        acc[mt][nt] = __builtin_amdgcn_mfma_f32_16x16x32_bf16(
            wa[mt][kh], xb[nt][kh], acc[mt][nt], 0, 0, 0);

  __syncthreads();  // sx staging dead; reuse as output transpose buffer
  // D[e][tok] -> sx[tok][e]: lane has tok=l16, e=mt*16+quad*4+reg (packed b64)
#pragma unroll
  for (int mt = 0; mt < 4; ++mt)
#pragma unroll
    for (int nt = 0; nt < 4; ++nt) {
      uint2 u;
      u.x = packbf(acc[mt][nt][0], acc[mt][nt][1]);
      u.y = packbf(acc[mt][nt][2], acc[mt][nt][3]);
      *(uint2*)&sx[(wid * 64 + nt * 16 + l16) * 72 + mt * 16 + quad * 4] = u;
    }
  __syncthreads();

  // coalesced store: thread t owns token tok0+t, writes its 128B row
  {
    const int tokg = tok0 + t;
    const int nb = tokg >> 12, l = tokg & 4095;
    uint4* orow = (uint4*)(dst + ((size_t)(nb * NH + h) * SL + l) * DH);
#pragma unroll
    for (int j = 0; j < 8; ++j) orow[j] = *(const uint4*)&sx[t * 72 + j * 8];
  }
}

// ---------------------------------------------------------------------------
// Kernel 2: flash-style MFMA windowed attention (unchanged from round 2).
// ---------------------------------------------------------------------------
__global__ __launch_bounds__(256) void attn_win_mfma(
    const ushort* __restrict__ qws, const ushort* __restrict__ kws,
    const ushort* __restrict__ vws, const int* __restrict__ mask,
    ushort* __restrict__ att) {
  __shared__ alignas(16) ushort sk[64 * 72];      // K chunk [key][d]
  __shared__ alignas(16) ushort svT[64 * 72];     // V chunk transposed [d][key]
  __shared__ alignas(16) ushort sp[4 * 64 * 72];  // per-wave P [q][key]
  __shared__ float sm[256];                       // per-query mask flag

  const int t = threadIdx.x;
  const int wid = t >> 6, lane = t & 63, quad = lane >> 4, l16 = lane & 15;
  const int bid = blockIdx.x;
  const int h = bid & 15, w = (bid >> 4) & 15, nb = bid >> 8;
  const size_t headbase = (size_t)(nb * NH + h) * SL;
  const int q0 = w * WIN + wid * 64;  // first query row of this wave

  sm[t] = (float)mask[nb * SL + w * WIN + t];

  short8 qf[4][2];
#pragma unroll
  for (int mt = 0; mt < 4; ++mt)
#pragma unroll
    for (int kh = 0; kh < 2; ++kh)
      qf[mt][kh] = *(const short8*)(qws + (headbase + q0 + mt * 16 + l16) * DH +
                                    kh * 32 + quad * 8);

  float4v Of[4][4];
#pragma unroll
  for (int mt = 0; mt < 4; ++mt)
#pragma unroll
    for (int dt = 0; dt < 4; ++dt) Of[mt][dt] = (float4v){0.f, 0.f, 0.f, 0.f};
  float mrow[16], lrow[16];
#pragma unroll
  for (int i = 0; i < 16; ++i) { mrow[i] = -INFINITY; lrow[i] = 0.f; }

  ushort* spw = sp + wid * 64 * 72;
  const int gk0 = w * WIN - OVL;
  const float CSC = 0.18033688f;  // 0.125 * log2(e)

  for (int c = 0; c < 5; ++c) {
    __syncthreads();
    const int cbase = gk0 + c * 64;
    for (int s = t; s < 512; s += 256) {
      int key = s & 63, dj = s >> 6;
      int gk = cbase + key;
      uint4 kq = make_uint4(0u, 0u, 0u, 0u);
      uint4 vq = make_uint4(0u, 0u, 0u, 0u);
      if ((unsigned)gk < (unsigned)SL) {
        kq = *(const uint4*)(kws + (headbase + gk) * DH + dj * 8);
        vq = *(const uint4*)(vws + (headbase + gk) * DH + dj * 8);
      }
      *(uint4*)&sk[key * 72 + dj * 8] = kq;
      svT[(dj * 8 + 0) * 72 + key] = (ushort)(kq.x & 0u) | (ushort)(vq.x & 0xffffu);
      svT[(dj * 8 + 1) * 72 + key] = (ushort)(vq.x >> 16);
      svT[(dj * 8 + 2) * 72 + key] = (ushort)(vq.y & 0xffffu);
      svT[(dj * 8 + 3) * 72 + key] = (ushort)(vq.y >> 16);
      svT[(dj * 8 + 4) * 72 + key] = (ushort)(vq.z & 0xffffu);
      svT[(dj * 8 + 5) * 72 + key] = (ushort)(vq.z >> 16);
      svT[(dj * 8 + 6) * 72 + key] = (ushort)(vq.w & 0xffffu);
      svT[(dj * 8 + 7) * 72 + key] = (ushort)(vq.w >> 16);
    }
    __syncthreads();

    float4v Sf[4][4];
#pragma unroll
    for (int mt = 0; mt < 4; ++mt)
#pragma unroll
      for (int nt = 0; nt < 4; ++nt) Sf[mt][nt] = (float4v){0.f, 0.f, 0.f, 0.f};
#pragma unroll
    for (int kh = 0; kh < 2; ++kh) {
      short8 kf[4];
#pragma unroll
      for (int nt = 0; nt < 4; ++nt)
        kf[nt] = *(const short8*)&sk[(nt * 16 + l16) * 72 + kh * 32 + quad * 8];
#pragma unroll
      for (int mt = 0; mt < 4; ++mt)
#pragma unroll
        for (int nt = 0; nt < 4; ++nt)
          Sf[mt][nt] = __builtin_amdgcn_mfma_f32_16x16x32_bf16(
              qf[mt][kh], kf[nt], Sf[mt][nt], 0, 0, 0);
    }

#pragma unroll
    for (int nt = 0; nt < 4; ++nt) {
      const int gkey = cbase + nt * 16 + l16;
      const bool kvalid = ((unsigned)gkey < (unsigned)SL);
#pragma unroll
      for (int mt = 0; mt < 4; ++mt)
#pragma unroll
        for (int reg = 0; reg < 4; ++reg) {
          float sv = Sf[mt][nt][reg] * CSC;
          if (sm[wid * 64 + mt * 16 + quad * 4 + reg] == 0.f) sv = -1.803e9f;
          if (!kvalid) sv = -INFINITY;
          Sf[mt][nt][reg] = sv;
        }
    }

#pragma unroll
    for (int mt = 0; mt < 4; ++mt)
#pragma unroll
      for (int reg = 0; reg < 4; ++reg) {
        const int ri = mt * 4 + reg;
        float mx = fmaxf(fmaxf(Sf[mt][0][reg], Sf[mt][1][reg]),
                         fmaxf(Sf[mt][2][reg], Sf[mt][3][reg]));
        mx = fmaxf(mx, __shfl_xor(mx, 1));
        mx = fmaxf(mx, __shfl_xor(mx, 2));
        mx = fmaxf(mx, __shfl_xor(mx, 4));
        mx = fmaxf(mx, __shfl_xor(mx, 8));
        const float mn = fmaxf(mrow[ri], mx);
        const float alpha = exp2f(mrow[ri] - mn);
        mrow[ri] = mn;
        float rs = 0.f;
#pragma unroll
        for (int nt = 0; nt < 4; ++nt) {
          float p = exp2f(Sf[mt][nt][reg] - mn);
          ushort pb = f2bf(p);
          rs += bf2f(pb);
          spw[(mt * 16 + quad * 4 + reg) * 72 + nt * 16 + l16] = pb;
        }
        rs += __shfl_xor(rs, 1);
        rs += __shfl_xor(rs, 2);
        rs += __shfl_xor(rs, 4);
        rs += __shfl_xor(rs, 8);
        lrow[ri] = lrow[ri] * alpha + rs;
#pragma unroll
        for (int dt = 0; dt < 4; ++dt) Of[mt][dt][reg] *= alpha;
      }

#pragma unroll
    for (int kh = 0; kh < 2; ++kh) {
      short8 pa[4], pb[4];
#pragma unroll
      for (int mt = 0; mt < 4; ++mt)
        pa[mt] = *(const short8*)&spw[(mt * 16 + l16) * 72 + kh * 32 + quad * 8];
#pragma unroll
      for (int dt = 0; dt < 4; ++dt)
        pb[dt] = *(const short8*)&svT[(dt * 16 + l16) * 72 + kh * 32 + quad * 8];
#pragma unroll
      for (int mt = 0; mt < 4; ++mt)
#pragma unroll
        for (int dt = 0; dt < 4; ++dt)
          Of[mt][dt] = __builtin_amdgcn_mfma_f32_16x16x32_bf16(
              pa[mt], pb[dt], Of[mt][dt], 0, 0, 0);
    }
  }

#pragma unroll
  for (int mt = 0; mt < 4; ++mt)
#pragma unroll
    for (int reg = 0; reg < 4; ++reg) {
      const float invl = 1.f / lrow[mt * 4 + reg];
      const size_t token = (size_t)nb * SL + q0 + mt * 16 + quad * 4 + reg;
#pragma unroll
      for (int dt = 0; dt < 4; ++dt)
        att[token * EMB + h * DH + dt * 16 + l16] =
            f2bf(Of[mt][dt][reg] * invl);
    }
}

// ---------------------------------------------------------------------------
// Kernel 3a: Wf fp32 -> bf16
// ---------------------------------------------------------------------------
__global__ __launch_bounds__(256) void wf_cvt(const float* __restrict__ Wf,
                                              ushort* __restrict__ o) {
  const int i = blockIdx.x * 256 + threadIdx.x;
  float4 f = ((const float4*)Wf)[i];
  uint2 u;
  u.x = packbf(f.x, f.y);
  u.y = packbf(f.z, f.w);
  ((uint2*)o)[i] = u;
}

// ---------------------------------------------------------------------------
// Kernel 3b: final GEMM (m97 structure, unchanged from round 2).
// ---------------------------------------------------------------------------
#define GBK 64
__global__ __launch_bounds__(256) void final_gemm_mfma(
    const ushort* __restrict__ A, const ushort* __restrict__ Bt,
    const float* __restrict__ bias, float* __restrict__ C) {
  __shared__ alignas(16) ushort sA[128 * GBK];
  __shared__ alignas(16) ushort sB[128 * GBK];
  const int t = threadIdx.x;
  const int wid = t >> 6, lane = t & 63, quad = lane >> 4, l16 = lane & 15;
  const int n0 = blockIdx.x * 128, m0 = blockIdx.y * 128;
  const int wm = (wid & 1) * 64, wn = (wid >> 1) * 64;

  float4v acc[4][4];
#pragma unroll
  for (int i = 0; i < 4; ++i)
#pragma unroll
    for (int j = 0; j < 4; ++j) acc[i][j] = (float4v){0.f, 0.f, 0.f, 0.f};

  const int arow = lane >> 3;
  const int acol = (lane & 7) * 8;

  for (int k0 = 0; k0 < EMB; k0 += GBK) {
    __syncthreads();
#pragma unroll
    for (int seg = 0; seg < 4; ++seg) {
      const int r = wid * 32 + seg * 8;
      __builtin_amdgcn_global_load_lds(
          (AS1 const void*)(A + (size_t)(m0 + r + arow) * EMB + k0 + acol),
          (AS3 void*)&sA[r * GBK], 16, 0, 0);
      __builtin_amdgcn_global_load_lds(
          (AS1 const void*)(Bt + (size_t)(n0 + r + arow) * EMB + k0 + acol),
          (AS3 void*)&sB[r * GBK], 16, 0, 0);
    }
    __syncthreads();
#pragma unroll
    for (int kk = 0; kk < GBK; kk += 32) {
      short8 af[4], bfr[4];
#pragma unroll
      for (int i = 0; i < 4; ++i)
        af[i] = *(const short8*)&sA[(wm + i * 16 + l16) * GBK + kk + quad * 8];
#pragma unroll
      for (int j = 0; j < 4; ++j)
        bfr[j] = *(const short8*)&sB[(wn + j * 16 + l16) * GBK + kk + quad * 8];
#pragma unroll
      for (int i = 0; i < 4; ++i)
#pragma unroll
        for (int j = 0; j < 4; ++j)
          acc[i][j] = __builtin_amdgcn_mfma_f32_16x16x32_bf16(af[i], bfr[j],
                                                              acc[i][j], 0, 0, 0);
    }
  }

  float bv[4];
#pragma unroll
  for (int j = 0; j < 4; ++j) bv[j] = bias[n0 + wn + j * 16 + l16];
#pragma unroll
  for (int i = 0; i < 4; ++i)
#pragma unroll
    for (int j = 0; j < 4; ++j)
#pragma unroll
      for (int r = 0; r < 4; ++r)
        C[(size_t)(m0 + wm + i * 16 + quad * 4 + r) * EMB + n0 + wn + j * 16 +
          l16] = acc[i][j][r] + bv[j];
}

extern "C" void kernel_launch(void* const* d_in, const int* in_sizes, int n_in,
                              void* d_out, int out_size, void* d_ws,
                              size_t ws_size, hipStream_t stream) {
  const float* values  = (const float*)d_in[0];
  const float* keys    = (const float*)d_in[1];
  const float* queries = (const float*)d_in[2];
  const int*   mask    = (const int*)d_in[3];
  const float* Wv = (const float*)d_in[4];
  const float* Wk = (const float*)d_in[5];
  const float* Wq = (const float*)d_in[6];
  const float* Wf = (const float*)d_in[7];
  const float* bfv = (const float*)d_in[8];
  float* out = (float*)d_out;

  ushort* ws = (ushort*)d_ws;
  ushort* q_ws = ws;
  ushort* k_ws = ws + (size_t)16777216;
  ushort* v_ws = ws + (size_t)33554432;
  ushort* a_ws = ws + (size_t)50331648;
  ushort* wf_bf = q_ws;  // q region dead after attn; stream-ordered reuse

  qkv_proj_mfma<<<dim3(NTOK / 256, NH, 3), 256, 0, stream>>>(
      queries, keys, values, Wq, Wk, Wv, q_ws, k_ws, v_ws);
  attn_win_mfma<<<NB * NW * NH, 256, 0, stream>>>(q_ws, k_ws, v_ws, mask, a_ws);
  wf_cvt<<<1024, 256, 0, stream>>>(Wf, wf_bf);
  final_gemm_mfma<<<dim3(EMB / 128, NTOK / 128), 256, 0, stream>>>(a_ws, wf_bf,
                                                                   bfv, out);
}